// Round 4
// baseline (1474.387 us; speedup 1.0000x reference)
//
#include <hip/hip_runtime.h>
#include <math.h>

typedef int    intx8    __attribute__((ext_vector_type(8)));   // 8 dwords = 32 fp8
typedef float  floatx16 __attribute__((ext_vector_type(16)));  // MFMA 32x32 C/D

#define N_ROWS 8192
#define H_DIM  1024
#define V_DIM  32000
#define V_PAD  32768         // padded V: pad cols killed via bias = -1e30
#define IGNORE_INDEX (-100)

#define S_SPLITS 16          // 16 splits x 16 tiles x 128 cols = 32768
#define TILES_PER_SPLIT 16
#define BM 128               // wave owns 32 rows x 128 cols -> acc[4] = 64 AGPR
#define BN 128
#define KSTEPS 8             // K-steps per tile (BK=128: 8 k-units of 16B)
#define TOTAL_STEPS (TILES_PER_SPLIT * KSTEPS)   // 128
#define BBUF (8 * 128 * 16)  // 16 KB per B step-buffer

#define LOG2E 1.4426950408889634f
#define LN2   0.6931471805599453f

// fp32 [R][1024] row-major -> fp8 e4m3 (value*scale), "unit-transposed"
// [64 k-units][Rstride][16B]. One thread per (u, r): 64B contiguous read, 16B coalesced write.
__global__ __launch_bounds__(256) void convert_fp8(const float* __restrict__ in,
                                                   unsigned char* __restrict__ out,
                                                   int Rstride, float scale) {
  const int r = blockIdx.x * 256 + threadIdx.x;
  const int u = blockIdx.y;                  // k-unit 0..63
  const float4* src = (const float4*)(in + (size_t)r * H_DIM + u * 16);
  uint4 res;
#pragma unroll
  for (int j = 0; j < 4; ++j) {
    const float4 v = src[j];
    int p = __builtin_amdgcn_cvt_pk_fp8_f32(v.x * scale, v.y * scale, 0, false);
    p = __builtin_amdgcn_cvt_pk_fp8_f32(v.z * scale, v.w * scale, p, true);
    ((int*)&res)[j] = p;
  }
  *(uint4*)(out + ((size_t)u * Rstride + r) * 16) = res;
}

// Padded bias, pre-scaled to base-2 domain. Pad cols get -1e30 -> exp2 -> 0
// (poisoned pad weights give finite acc; -1e30 dominates).
__global__ __launch_bounds__(256) void pad_bias(const float* __restrict__ bias,
                                                float* __restrict__ biasp) {
  const int i = blockIdx.x * 256 + threadIdx.x;
  biasp[i] = (i < V_DIM) ? bias[i] * LOG2E : -1e30f;
}

// Fused GEMM + sumexp. fp8 e4m3, x pre-scaled by log2e (base-2 softmax domain).
// mfma_scale_f32_32x32x64_f8f6f4, unity scales (0x7F = E8M0 2^0).
//
// Round-4 structure -- attack the occupancy wall:
//  * R0-R3 all ran 256 regs/wave (128 arch + 128 AGPR acc) = 2 waves/SIMD;
//    every schedule variant pinned at 37-44% MfmaUtil because all resident
//    waves were barrier-locked in lockstep with nothing to hide latency.
//  * BM=128: wave owns 32x128 -> acc[4] = 64 AGPR. __launch_bounds__(256,3)
//    caps total regs at ~170/wave -> 3 blocks/CU, 12 waves/CU. Cross-block
//    wave overlap (m114) absorbs the per-step barrier bubbles.
//  * BK=128 (R0's proven step size): 128 barrier-steps, 8 MFMA/wave/step.
//  * A stays in registers (R3): zero intra-block reuse, [u][row][16B] layout
//    gives per-lane contiguous 16B loads; k0-half prefetched one step ahead,
//    k1-half loaded in-step (L2-resident, covered by the first 4 MFMAs).
//  * B in LDS (128-row reuse), 2-deep, ONE __syncthreads per step (drains
//    BDMA(t)+A prefetch, publishes B(t), proves t-1 reads retired -> BDMA(t+1)
//    into buf[(t+1)&1] is WAR-safe).
//  * NO XCD swizzle: default linear mapping keeps each XCD's A working set at
//    8 row-slices = 1 MB (L2-resident across the 16x per-tile re-reads).
//    R3's split-per-XCD swizzle put 8MB of A on each L2 -> FETCH 136->621 MB.
// Per-lane K-accumulation order identical to R0-R3 -> bitwise identical.

typedef union { intx8 v; uint4 q[2]; } frag;

#define BDMA(T) do {                                                                     \
    const int _t = (T);                                                                  \
    const int _ub = (_t & 7) * 8;                                                        \
    const int _n0 = (sidx * TILES_PER_SPLIT + (_t >> 3)) * BN;                           \
    unsigned char* _d = smB + ((_t & 1) ? BBUF : 0);                                     \
    _Pragma("unroll")                                                                    \
    for (int _j = 0; _j < 4; ++_j) {                                                     \
      const int _c = _j * 4 + w, _u = _c >> 1, _rb = _c & 1;                             \
      __builtin_amdgcn_global_load_lds(                                                  \
          (const __attribute__((address_space(1))) void*)(wsb +                          \
              ((size_t)(_ub + _u) * V_PAD + _n0 + _rb * 64 + lane) * 16),                \
          (__attribute__((address_space(3))) void*)(_d + ((_u * 128 + _rb * 64 + lane) * 16)), \
          16, 0, 0);                                                                     \
    }                                                                                    \
  } while (0)

// One K-step: 2 MFMA sub-steps of K=64. AK0 holds this step's k0 frag (loaded
// last step); AK0N receives next step's k0 prefetch; k1 frag loaded in-step.
#define STEP(T, AK0, AK0N) do {                                                          \
    const int _st = (T);                                                                 \
    __syncthreads();   /* drains BDMA(_st) + A prefetch; publishes B(_st) */             \
    if (_st + 1 < TOTAL_STEPS) BDMA(_st + 1);                                            \
    frag aK1;          /* in-step k1 half: L2-resident, hidden by first MFMAs */         \
    {                                                                                    \
      const size_t _u1 = (size_t)((_st & 7) * 8 + 4 + half2);                            \
      aK1.q[0] = *(const uint4*)(xs + ((_u1 * N_ROWS + arow) * 16));                     \
      aK1.q[1] = *(const uint4*)(xs + (((_u1 + 1) * N_ROWS + arow) * 16));               \
    }                                                                                    \
    if (_st + 1 < TOTAL_STEPS) {                                                         \
      const size_t _u0 = (size_t)(((_st + 1) & 7) * 8 + half2);                          \
      AK0N.q[0] = *(const uint4*)(xs + ((_u0 * N_ROWS + arow) * 16));                    \
      AK0N.q[1] = *(const uint4*)(xs + (((_u0 + 1) * N_ROWS + arow) * 16));              \
    }                                                                                    \
    const unsigned char* _pB = smB + ((_st & 1) ? BBUF : 0);                             \
    frag b0[4];                                                                          \
    _Pragma("unroll")                                                                    \
    for (int nb = 0; nb < 4; ++nb) {                                                     \
      b0[nb].q[0] = *(const uint4*)(_pB + (((half2    ) * 128 + nb * 32 + l31) * 16));   \
      b0[nb].q[1] = *(const uint4*)(_pB + (((half2 + 1) * 128 + nb * 32 + l31) * 16));   \
    }                                                                                    \
    __builtin_amdgcn_s_setprio(1);                                                       \
    _Pragma("unroll")                                                                    \
    for (int nb = 0; nb < 4; ++nb)                                                       \
      acc[nb] = __builtin_amdgcn_mfma_scale_f32_32x32x64_f8f6f4(                         \
          AK0.v, b0[nb].v, acc[nb], 0, 0, 0, 0x7F7F7F7F, 0, 0x7F7F7F7F);                 \
    __builtin_amdgcn_s_setprio(0);                                                       \
    frag b1[4];                                                                          \
    _Pragma("unroll")                                                                    \
    for (int nb = 0; nb < 4; ++nb) {                                                     \
      b1[nb].q[0] = *(const uint4*)(_pB + (((4 + half2) * 128 + nb * 32 + l31) * 16));   \
      b1[nb].q[1] = *(const uint4*)(_pB + (((5 + half2) * 128 + nb * 32 + l31) * 16));   \
    }                                                                                    \
    __builtin_amdgcn_s_setprio(1);                                                       \
    _Pragma("unroll")                                                                    \
    for (int nb = 0; nb < 4; ++nb)                                                       \
      acc[nb] = __builtin_amdgcn_mfma_scale_f32_32x32x64_f8f6f4(                         \
          aK1.v, b1[nb].v, acc[nb], 0, 0, 0, 0x7F7F7F7F, 0, 0x7F7F7F7F);                 \
    __builtin_amdgcn_s_setprio(0);                                                       \
  } while (0)

__global__ __launch_bounds__(256, 3) void flce_main(const unsigned char* __restrict__ xs,
                                                    const unsigned char* __restrict__ wsb,
                                                    const float* __restrict__ biasp,
                                                    float* __restrict__ partials) {
  __shared__ __align__(16) unsigned char smB[2 * BBUF];   // 32KB: 2-deep B only

  const int tid  = threadIdx.x;
  const int lane = tid & 63;
  const int w    = tid >> 6;      // wave 0..3: rows [w*32, w*32+32)
  const int l31  = lane & 31;
  const int half = lane >> 5;     // k-half within MFMA (32 k each)
  const int half2 = half * 2;
  const int row0 = blockIdx.x * BM;
  const int sidx = blockIdx.y;

  const size_t arow = (size_t)(row0 + w * 32 + l31);   // one A row per lane

  float l_state[16];              // per-lane Σ 2^v over its 128 cols, 16 acc slots
#pragma unroll
  for (int i = 0; i < 16; ++i) l_state[i] = 0.f;

  frag aE, aO;

  // Prologue: stage step 0 (B->LDS, A k0->regs). First sync drains them.
  BDMA(0);
  {
    const size_t _u0 = (size_t)half2;
    aE.q[0] = *(const uint4*)(xs + ((_u0 * N_ROWS + arow) * 16));
    aE.q[1] = *(const uint4*)(xs + (((_u0 + 1) * N_ROWS + arow) * 16));
  }

#pragma unroll 1
  for (int ct = 0; ct < TILES_PER_SPLIT; ++ct) {
    floatx16 acc[4];
#pragma unroll
    for (int nb = 0; nb < 4; ++nb)
#pragma unroll
      for (int i = 0; i < 16; ++i) acc[nb][i] = 0.f;

#pragma unroll 1
    for (int ks2 = 0; ks2 < 4; ++ks2) {        // 8 K-steps, x2 so A-sets are static
      const int st0 = ct * KSTEPS + ks2 * 2;   // even -> aE used, aO prefetched
      STEP(st0,     aE, aO);
      STEP(st0 + 1, aO, aE);
    }

    // Epilogue: Σ 2^(acc + bias2). C/D 32x32 layout [m74/m101]:
    // col = nb*32 + l31, row = w*32 + 4*half + (r&3) + 8*(r>>2).
    const int n0 = (sidx * TILES_PER_SPLIT + ct) * BN;
    float bnb[4];
#pragma unroll
    for (int nb = 0; nb < 4; ++nb) bnb[nb] = biasp[n0 + nb * 32 + l31];
#pragma unroll
    for (int r = 0; r < 16; ++r) {
      float s = exp2f(acc[0][r] + bnb[0]) + exp2f(acc[1][r] + bnb[1])
              + exp2f(acc[2][r] + bnb[2]) + exp2f(acc[3][r] + bnb[3]);
      l_state[r] += s;
    }
  }

  // Sum over this wave's 128 cols: butterfly within the 32-lane half (rows differ per half).
#pragma unroll
  for (int s = 0; s < 16; ++s) {
    float v = l_state[s];
#pragma unroll
    for (int off = 1; off < 32; off <<= 1) v += __shfl_xor(v, off, 64);
    l_state[s] = v;
  }

  // Each wave owns all cols of its 32 rows -> direct write, no cross-wave combine.
  if (l31 == 0) {
#pragma unroll
    for (int s = 0; s < 16; ++s) {
      const int row = w * 32 + 4 * half + (s & 3) + 8 * (s >> 2);
      partials[(size_t)(row0 + row) * S_SPLITS + sidx] = l_state[s];
    }
  }
}

// Exact fp32 target logit: one wave per row.
__global__ __launch_bounds__(256) void tgt_kernel(const float* __restrict__ x,
                                                  const float* __restrict__ wgt,
                                                  const float* __restrict__ bias,
                                                  const int* __restrict__ target,
                                                  float* __restrict__ tgt_logit) {
  const int r = blockIdx.x * 4 + (threadIdx.x >> 6);
  const int lane = threadIdx.x & 63;
  const int t = target[r];
  const int tt = (t == IGNORE_INDEX) ? 0 : t;
  const float4* xr = (const float4*)(x + (size_t)r * H_DIM);
  const float4* wr = (const float4*)(wgt + (size_t)tt * H_DIM);
  float acc = 0.f;
#pragma unroll
  for (int i = 0; i < 4; ++i) {
    const float4 a = xr[lane + i * 64];
    const float4 b = wr[lane + i * 64];
    acc += a.x * b.x + a.y * b.y + a.z * b.z + a.w * b.w;
  }
#pragma unroll
  for (int off = 32; off >= 1; off >>= 1) acc += __shfl_xor(acc, off, 64);
  if (lane == 0) tgt_logit[r] = acc + bias[tt];
}

// Per-row loss + per-block partial sums. partials hold Σ2^v per (row, split):
// lse_nat = ln2 * log2(Σ_s l_s).
__global__ __launch_bounds__(256) void loss_rows(const float* __restrict__ partials,
                                                 const float* __restrict__ tgt_logit,
                                                 const int* __restrict__ target,
                                                 float* __restrict__ bsums) {
  const int r = blockIdx.x * 256 + threadIdx.x;
  float l = 0.f;
#pragma unroll
  for (int s = 0; s < S_SPLITS; ++s) l += partials[(size_t)r * S_SPLITS + s];
  const float lse = LN2 * __log2f(l);
  const bool valid = (target[r] != IGNORE_INDEX);
  float loss = valid ? (lse - tgt_logit[r]) : 0.f;
  float cnt  = valid ? 1.f : 0.f;
  const int lane = threadIdx.x & 63;
  const int w = threadIdx.x >> 6;
#pragma unroll
  for (int off = 32; off >= 1; off >>= 1) {
    loss += __shfl_xor(loss, off, 64);
    cnt  += __shfl_xor(cnt, off, 64);
  }
  __shared__ float sl[4], sc[4];
  if (lane == 0) { sl[w] = loss; sc[w] = cnt; }
  __syncthreads();
  if (threadIdx.x == 0) {
    float S = 0.f, C = 0.f;
    for (int i = 0; i < 4; ++i) { S += sl[i]; C += sc[i]; }
    bsums[blockIdx.x] = S;
    bsums[32 + blockIdx.x] = C;
  }
}

__global__ void finalize(const float* __restrict__ bsums, float* __restrict__ out) {
  const int t = threadIdx.x;  // 64 threads
  float s = (t < 32) ? bsums[t] : 0.f;
  float c = (t < 32) ? bsums[32 + t] : 0.f;
#pragma unroll
  for (int off = 32; off >= 1; off >>= 1) {
    s += __shfl_xor(s, off, 64);
    c += __shfl_xor(c, off, 64);
  }
  if (t == 0) out[0] = s / fmaxf(c, 1.f);
}

extern "C" void kernel_launch(void* const* d_in, const int* in_sizes, int n_in,
                              void* d_out, int out_size, void* d_ws, size_t ws_size,
                              hipStream_t stream) {
  const float* x    = (const float*)d_in[0];
  const float* wgt  = (const float*)d_in[1];
  const float* bias = (const float*)d_in[2];
  const int*   tgt  = (const int*)d_in[3];
  float* out = (float*)d_out;

  char* ws = (char*)d_ws;
  const size_t XS8 = (size_t)N_ROWS * H_DIM;        // 8 MB fp8 x (pre-scaled by log2e)
  const size_t WS8 = (size_t)V_PAD * H_DIM;         // 33.5 MB fp8 W (rows >= V_DIM stay poisoned)
  const size_t BP  = (size_t)V_PAD * 4;             // padded bias (base-2 domain)
  const size_t PB  = (size_t)N_ROWS * S_SPLITS * 4; // per-(row,split) sumexp
  unsigned char* xs8 = (unsigned char*)ws;
  unsigned char* ws8 = (unsigned char*)(ws + XS8);
  float* biasp    = (float*)(ws + XS8 + WS8);
  float* partials = (float*)(ws + XS8 + WS8 + BP);
  float* tgt_lg   = (float*)(ws + XS8 + WS8 + BP + PB);
  float* bsums    = (float*)(ws + XS8 + WS8 + BP + PB + (size_t)N_ROWS * 4);

  convert_fp8<<<dim3(N_ROWS / 256, H_DIM / 16), 256, 0, stream>>>(x, xs8, N_ROWS, LOG2E);
  convert_fp8<<<dim3(V_DIM / 256, H_DIM / 16), 256, 0, stream>>>(wgt, ws8, V_PAD, 1.0f);
  pad_bias<<<V_PAD / 256, 256, 0, stream>>>(bias, biasp);
  tgt_kernel<<<N_ROWS / 4, 256, 0, stream>>>(x, wgt, bias, tgt, tgt_lg);
  flce_main<<<dim3(N_ROWS / BM, S_SPLITS), 256, 0, stream>>>(xs8, ws8, biasp, partials);
  loss_rows<<<N_ROWS / 256, 256, 0, stream>>>(partials, tgt_lg, tgt, bsums);
  finalize<<<1, 64, 0, stream>>>(bsums, out);
}

// Round 5
// 495.666 us; speedup vs baseline: 2.9746x; 2.9746x over previous
//
#include <hip/hip_runtime.h>
#include <math.h>

typedef int    intx8    __attribute__((ext_vector_type(8)));   // 8 dwords = 32 fp8
typedef float  floatx16 __attribute__((ext_vector_type(16)));  // MFMA 32x32 C/D

#define N_ROWS 8192
#define H_DIM  1024
#define V_DIM  32000
#define V_PAD  32768         // padded V: pad cols killed via bias = -1e30
#define IGNORE_INDEX (-100)

#define S_SPLITS 16          // 16 splits x 16 tiles x 128 cols = 32768
#define TILES_PER_SPLIT 16
#define BM 256
#define BN 128
#define KSTEPS 8             // K-steps per tile (BK=128: 8 k-units of 16B)
#define TOTAL_STEPS (TILES_PER_SPLIT * KSTEPS)   // 128
#define BBUF (8 * 128 * 16)  // 16 KB per B step-buffer

#define LOG2E 1.4426950408889634f
#define LN2   0.6931471805599453f

// fp32 [R][1024] row-major -> fp8 e4m3 (value*scale), "unit-transposed"
// [64 k-units][Rstride][16B]. One thread per (u, r): 64B contiguous read, 16B coalesced write.
__global__ __launch_bounds__(256) void convert_fp8(const float* __restrict__ in,
                                                   unsigned char* __restrict__ out,
                                                   int Rstride, float scale) {
  const int r = blockIdx.x * 256 + threadIdx.x;
  const int u = blockIdx.y;                  // k-unit 0..63
  const float4* src = (const float4*)(in + (size_t)r * H_DIM + u * 16);
  uint4 res;
#pragma unroll
  for (int j = 0; j < 4; ++j) {
    const float4 v = src[j];
    int p = __builtin_amdgcn_cvt_pk_fp8_f32(v.x * scale, v.y * scale, 0, false);
    p = __builtin_amdgcn_cvt_pk_fp8_f32(v.z * scale, v.w * scale, p, true);
    ((int*)&res)[j] = p;
  }
  *(uint4*)(out + ((size_t)u * Rstride + r) * 16) = res;
}

// Padded bias, pre-scaled to base-2 domain. Pad cols get -1e30 -> exp2 -> 0
// (poisoned pad weights give finite acc; -1e30 dominates).
__global__ __launch_bounds__(256) void pad_bias(const float* __restrict__ bias,
                                                float* __restrict__ biasp) {
  const int i = blockIdx.x * 256 + threadIdx.x;
  biasp[i] = (i < V_DIM) ? bias[i] * LOG2E : -1e30f;
}

// Fused GEMM + sumexp. fp8 e4m3, x pre-scaled by log2e (base-2 softmax domain).
// mfma_scale_f32_32x32x64_f8f6f4, unity scales (0x7F = E8M0 2^0).
//
// Round-5 structure (= R0 skeleton + A-LDS removal):
//  * Register model from R0-R4: at 2 blocks/CU the per-wave budget is 256
//    unified regs; acc[2][4] = 128 AGPR leaves EXACTLY 128 arch VGPRs. This
//    kernel's arch working set: l_state 32 + aK0 16 + aK1 16 + b 32 + addr
//    ~ 116 -> no spill (WRITE_SIZE must stay ~0.6 MB; that's the check).
//  * A is NOT staged in LDS: zero intra-block reuse (each wave owns its 64
//    rows) and the [u][row][16B] layout gives per-lane contiguous 16B global
//    loads (512B per 32-lane group), L2-served. This cuts the LDS pipe per
//    CU-slot from ~3000 to ~1750 cyc vs MFMA 2200 (R0 serialized both).
//  * B keeps LDS (4x intra-block reuse), 2-deep, ONE __syncthreads per step.
//    The sync at top of step t drains vmcnt(0), but the newest outstanding op
//    is BDMA(t) issued a full step earlier -> drain is free. It also proves
//    all waves retired their step t-1 ds_reads (lgkm-waited before their t-1
//    MFMAs) -> BDMA(t+1) into buf[(t+1)&1] right after the sync is WAR-safe.
//  * NO XCD swizzle (R3 lesson): default linear mapping keeps each XCD's A
//    working set at ~1MB (L2-resident across the 16x per-tile A re-reads).
// Per-lane K-accumulation order identical to R0 (units half2,half2+1 then
// 4+half2,5+half2 within each BK=128 step) -> bitwise identical, absmax 0.

typedef union { intx8 v; uint4 q[2]; } frag;

#define BDMA(T) do {                                                                     \
    const int _t = (T);                                                                  \
    const int _ub = (_t & 7) * 8;                                                        \
    const int _n0 = (sidx * TILES_PER_SPLIT + (_t >> 3)) * BN;                           \
    unsigned char* _d = smB + ((_t & 1) ? BBUF : 0);                                     \
    _Pragma("unroll")                                                                    \
    for (int _j = 0; _j < 4; ++_j) {                                                     \
      const int _c = _j * 4 + w, _u = _c >> 1, _rb = _c & 1;                             \
      __builtin_amdgcn_global_load_lds(                                                  \
          (const __attribute__((address_space(1))) void*)(wsb +                          \
              ((size_t)(_ub + _u) * V_PAD + _n0 + _rb * 64 + lane) * 16),                \
          (__attribute__((address_space(3))) void*)(_d + ((_u * 128 + _rb * 64 + lane) * 16)), \
          16, 0, 0);                                                                     \
    }                                                                                    \
  } while (0)

__global__ __launch_bounds__(256, 2) void flce_main(const unsigned char* __restrict__ xs,
                                                    const unsigned char* __restrict__ wsb,
                                                    const float* __restrict__ biasp,
                                                    float* __restrict__ partials) {
  __shared__ __align__(16) unsigned char smB[2 * BBUF];   // 32KB: 2-deep B only

  const int tid  = threadIdx.x;
  const int lane = tid & 63;
  const int w    = tid >> 6;      // wave 0..3: rows [w*64, w*64+64)
  const int l31  = lane & 31;
  const int half = lane >> 5;     // k-half within MFMA (32 k each)
  const int half2 = half * 2;
  const int wr   = w * 64;
  const int row0 = blockIdx.x * BM;
  const int sidx = blockIdx.y;

  const size_t arow0 = (size_t)(row0 + wr + l31);   // A row for mb=0
  const size_t arow1 = arow0 + 32;                  // A row for mb=1

  float l_state[32];              // slot = mb*16 + reg; per-lane Σ 2^v over its cols
#pragma unroll
  for (int i = 0; i < 32; ++i) l_state[i] = 0.f;

  // Prologue: stage B for step 0. First sync drains it (only cold-start exposure).
  BDMA(0);

#pragma unroll 1
  for (int ct = 0; ct < TILES_PER_SPLIT; ++ct) {
    floatx16 acc[2][4];
#pragma unroll
    for (int mb = 0; mb < 2; ++mb)
#pragma unroll
      for (int nb = 0; nb < 4; ++nb)
#pragma unroll
        for (int i = 0; i < 16; ++i) acc[mb][nb][i] = 0.f;

#pragma unroll 1
    for (int k0i = 0; k0i < KSTEPS; ++k0i) {
      const int st = ct * KSTEPS + k0i;
      const int ub = k0i * 8;

      __syncthreads();   // drains BDMA(st) (1 step old, free); publishes B(st);
                         // proves all waves retired step st-1 ds_reads
      if (st + 1 < TOTAL_STEPS) BDMA(st + 1);   // into buf[(st+1)&1]: WAR-safe

      // A fragments global->VGPR (L2-resident; latency hidden under b ds_reads).
      frag aK0[2], aK1[2];
      {
        const size_t u0 = (size_t)(ub + half2);
        const size_t u1 = (size_t)(ub + 4 + half2);
        aK0[0].q[0] = *(const uint4*)(xs + ((u0 * N_ROWS + arow0) * 16));
        aK0[0].q[1] = *(const uint4*)(xs + (((u0 + 1) * N_ROWS + arow0) * 16));
        aK0[1].q[0] = *(const uint4*)(xs + ((u0 * N_ROWS + arow1) * 16));
        aK0[1].q[1] = *(const uint4*)(xs + (((u0 + 1) * N_ROWS + arow1) * 16));
        aK1[0].q[0] = *(const uint4*)(xs + ((u1 * N_ROWS + arow0) * 16));
        aK1[0].q[1] = *(const uint4*)(xs + (((u1 + 1) * N_ROWS + arow0) * 16));
        aK1[1].q[0] = *(const uint4*)(xs + ((u1 * N_ROWS + arow1) * 16));
        aK1[1].q[1] = *(const uint4*)(xs + (((u1 + 1) * N_ROWS + arow1) * 16));
      }

      const unsigned char* pB = smB + ((st & 1) ? BBUF : 0);

      {  // sub-step 0: K-units ub+half2, ub+half2+1
        frag b[4];
#pragma unroll
        for (int nb = 0; nb < 4; ++nb) {
          b[nb].q[0] = *(const uint4*)(pB + (((half2    ) * 128 + nb * 32 + l31) * 16));
          b[nb].q[1] = *(const uint4*)(pB + (((half2 + 1) * 128 + nb * 32 + l31) * 16));
        }
        __builtin_amdgcn_s_setprio(1);
#pragma unroll
        for (int mb = 0; mb < 2; ++mb)
#pragma unroll
          for (int nb = 0; nb < 4; ++nb)
            acc[mb][nb] = __builtin_amdgcn_mfma_scale_f32_32x32x64_f8f6f4(
                aK0[mb].v, b[nb].v, acc[mb][nb],
                0, 0, 0, 0x7F7F7F7F, 0, 0x7F7F7F7F);
        __builtin_amdgcn_s_setprio(0);
      }
      {  // sub-step 1: K-units ub+4+half2, ub+5+half2
        frag b[4];
#pragma unroll
        for (int nb = 0; nb < 4; ++nb) {
          b[nb].q[0] = *(const uint4*)(pB + (((4 + half2) * 128 + nb * 32 + l31) * 16));
          b[nb].q[1] = *(const uint4*)(pB + (((5 + half2) * 128 + nb * 32 + l31) * 16));
        }
        __builtin_amdgcn_s_setprio(1);
#pragma unroll
        for (int mb = 0; mb < 2; ++mb)
#pragma unroll
          for (int nb = 0; nb < 4; ++nb)
            acc[mb][nb] = __builtin_amdgcn_mfma_scale_f32_32x32x64_f8f6f4(
                aK1[mb].v, b[nb].v, acc[mb][nb],
                0, 0, 0, 0x7F7F7F7F, 0, 0x7F7F7F7F);
        __builtin_amdgcn_s_setprio(0);
      }
    }

    // Epilogue: Σ 2^(acc + bias2). C/D 32x32 layout [m74/m101]:
    // col = nb*32 + l31, row = wr + mb*32 + 4*half + (r&3) + 8*(r>>2).
    const int n0 = (sidx * TILES_PER_SPLIT + ct) * BN;
    float bnb[4];
#pragma unroll
    for (int nb = 0; nb < 4; ++nb) bnb[nb] = biasp[n0 + nb * 32 + l31];
#pragma unroll
    for (int mb = 0; mb < 2; ++mb)
#pragma unroll
      for (int r = 0; r < 16; ++r) {
        float s = exp2f(acc[mb][0][r] + bnb[0]) + exp2f(acc[mb][1][r] + bnb[1])
                + exp2f(acc[mb][2][r] + bnb[2]) + exp2f(acc[mb][3][r] + bnb[3]);
        l_state[mb * 16 + r] += s;
      }
  }

  // Sum over this wave's 128 cols: butterfly within the 32-lane half (rows differ per half).
#pragma unroll
  for (int s = 0; s < 32; ++s) {
    float v = l_state[s];
#pragma unroll
    for (int off = 1; off < 32; off <<= 1) v += __shfl_xor(v, off, 64);
    l_state[s] = v;
  }

  // Each wave owns all cols of its 64 rows -> direct write, no cross-wave combine.
  if (l31 == 0) {
#pragma unroll
    for (int s = 0; s < 32; ++s) {
      const int mb = s >> 4, r = s & 15;
      const int row = wr + mb * 32 + 4 * half + (r & 3) + 8 * (r >> 2);
      partials[(size_t)(row0 + row) * S_SPLITS + sidx] = l_state[s];
    }
  }
}

// Exact fp32 target logit: one wave per row.
__global__ __launch_bounds__(256) void tgt_kernel(const float* __restrict__ x,
                                                  const float* __restrict__ wgt,
                                                  const float* __restrict__ bias,
                                                  const int* __restrict__ target,
                                                  float* __restrict__ tgt_logit) {
  const int r = blockIdx.x * 4 + (threadIdx.x >> 6);
  const int lane = threadIdx.x & 63;
  const int t = target[r];
  const int tt = (t == IGNORE_INDEX) ? 0 : t;
  const float4* xr = (const float4*)(x + (size_t)r * H_DIM);
  const float4* wr = (const float4*)(wgt + (size_t)tt * H_DIM);
  float acc = 0.f;
#pragma unroll
  for (int i = 0; i < 4; ++i) {
    const float4 a = xr[lane + i * 64];
    const float4 b = wr[lane + i * 64];
    acc += a.x * b.x + a.y * b.y + a.z * b.z + a.w * b.w;
  }
#pragma unroll
  for (int off = 32; off >= 1; off >>= 1) acc += __shfl_xor(acc, off, 64);
  if (lane == 0) tgt_logit[r] = acc + bias[tt];
}

// Per-row loss + per-block partial sums. partials hold Σ2^v per (row, split):
// lse_nat = ln2 * log2(Σ_s l_s).
__global__ __launch_bounds__(256) void loss_rows(const float* __restrict__ partials,
                                                 const float* __restrict__ tgt_logit,
                                                 const int* __restrict__ target,
                                                 float* __restrict__ bsums) {
  const int r = blockIdx.x * 256 + threadIdx.x;
  float l = 0.f;
#pragma unroll
  for (int s = 0; s < S_SPLITS; ++s) l += partials[(size_t)r * S_SPLITS + s];
  const float lse = LN2 * __log2f(l);
  const bool valid = (target[r] != IGNORE_INDEX);
  float loss = valid ? (lse - tgt_logit[r]) : 0.f;
  float cnt  = valid ? 1.f : 0.f;
  const int lane = threadIdx.x & 63;
  const int w = threadIdx.x >> 6;
#pragma unroll
  for (int off = 32; off >= 1; off >>= 1) {
    loss += __shfl_xor(loss, off, 64);
    cnt  += __shfl_xor(cnt, off, 64);
  }
  __shared__ float sl[4], sc[4];
  if (lane == 0) { sl[w] = loss; sc[w] = cnt; }
  __syncthreads();
  if (threadIdx.x == 0) {
    float S = 0.f, C = 0.f;
    for (int i = 0; i < 4; ++i) { S += sl[i]; C += sc[i]; }
    bsums[blockIdx.x] = S;
    bsums[32 + blockIdx.x] = C;
  }
}

__global__ void finalize(const float* __restrict__ bsums, float* __restrict__ out) {
  const int t = threadIdx.x;  // 64 threads
  float s = (t < 32) ? bsums[t] : 0.f;
  float c = (t < 32) ? bsums[32 + t] : 0.f;
#pragma unroll
  for (int off = 32; off >= 1; off >>= 1) {
    s += __shfl_xor(s, off, 64);
    c += __shfl_xor(c, off, 64);
  }
  if (t == 0) out[0] = s / fmaxf(c, 1.f);
}

extern "C" void kernel_launch(void* const* d_in, const int* in_sizes, int n_in,
                              void* d_out, int out_size, void* d_ws, size_t ws_size,
                              hipStream_t stream) {
  const float* x    = (const float*)d_in[0];
  const float* wgt  = (const float*)d_in[1];
  const float* bias = (const float*)d_in[2];
  const int*   tgt  = (const int*)d_in[3];
  float* out = (float*)d_out;

  char* ws = (char*)d_ws;
  const size_t XS8 = (size_t)N_ROWS * H_DIM;        // 8 MB fp8 x (pre-scaled by log2e)
  const size_t WS8 = (size_t)V_PAD * H_DIM;         // 33.5 MB fp8 W (rows >= V_DIM stay poisoned)
  const size_t BP  = (size_t)V_PAD * 4;             // padded bias (base-2 domain)
  const size_t PB  = (size_t)N_ROWS * S_SPLITS * 4; // per-(row,split) sumexp
  unsigned char* xs8 = (unsigned char*)ws;
  unsigned char* ws8 = (unsigned char*)(ws + XS8);
  float* biasp    = (float*)(ws + XS8 + WS8);
  float* partials = (float*)(ws + XS8 + WS8 + BP);
  float* tgt_lg   = (float*)(ws + XS8 + WS8 + BP + PB);
  float* bsums    = (float*)(ws + XS8 + WS8 + BP + PB + (size_t)N_ROWS * 4);

  convert_fp8<<<dim3(N_ROWS / 256, H_DIM / 16), 256, 0, stream>>>(x, xs8, N_ROWS, LOG2E);
  convert_fp8<<<dim3(V_DIM / 256, H_DIM / 16), 256, 0, stream>>>(wgt, ws8, V_PAD, 1.0f);
  pad_bias<<<V_PAD / 256, 256, 0, stream>>>(bias, biasp);
  tgt_kernel<<<N_ROWS / 4, 256, 0, stream>>>(x, wgt, bias, tgt, tgt_lg);
  flce_main<<<dim3(N_ROWS / BM, S_SPLITS), 256, 0, stream>>>(xs8, ws8, biasp, partials);
  loss_rows<<<N_ROWS / 256, 256, 0, stream>>>(partials, tgt_lg, tgt, bsums);
  finalize<<<1, 64, 0, stream>>>(bsums, out);
}